// Round 1
// baseline (849.507 us; speedup 1.0000x reference)
//
#include <hip/hip_runtime.h>
#include <hip/hip_bf16.h>
#include <math.h>

#define NPIX 2304      // 48*48
#define HW 48
#define CDIM 256
#define NHEADS 8
#define HD 32
#define SCALE_CONST 0.17677669529663687f   // 32^-0.5

// ---------------------------------------------------------------------------
// Generic 1x1-conv GEMM:  Y[b,o,n] = sum_c W[o,c] * (X[b,c,n] (+ Xadd[b,c,n])) + bias[o]
// block = 256 threads (16x16), tile 64(o) x 64(n), K-chunk 16.
// ---------------------------------------------------------------------------
__global__ __launch_bounds__(256) void conv1x1_kernel(
    const float* __restrict__ W,     // [M][CDIM]
    const float* __restrict__ bias,  // [M]
    const float* __restrict__ X,     // [B][CDIM][NPIX]
    const float* __restrict__ Xadd,  // nullable, same shape as X
    float* __restrict__ Y,           // [B][M][NPIX]
    int M)
{
    __shared__ float sW[16][65];   // [kc][o]
    __shared__ float sX[16][65];   // [kc][n]
    const int b  = blockIdx.z;
    const int o0 = blockIdx.y * 64;
    const int n0 = blockIdx.x * 64;
    const int t  = threadIdx.x;
    const int tx = t & 15;         // n sub-index
    const int ty = t >> 4;         // o sub-index

    const float* Xb  = X + (size_t)b * CDIM * NPIX;
    const float* Xab = Xadd ? Xadd + (size_t)b * CDIM * NPIX : nullptr;

    float acc[4][4] = {};

    for (int k0 = 0; k0 < CDIM; k0 += 16) {
        // load W chunk: 64 o x 16 kc
#pragma unroll
        for (int i = 0; i < 4; ++i) {
            int idx = t + i * 256;
            int o = idx >> 4, kc = idx & 15;
            sW[kc][o] = W[(size_t)(o0 + o) * CDIM + k0 + kc];
        }
        // load X chunk: 16 kc x 64 n (coalesced)
#pragma unroll
        for (int i = 0; i < 4; ++i) {
            int idx = t + i * 256;
            int kc = idx >> 6, n = idx & 63;
            float v = Xb[(size_t)(k0 + kc) * NPIX + n0 + n];
            if (Xab) v += Xab[(size_t)(k0 + kc) * NPIX + n0 + n];
            sX[kc][n] = v;
        }
        __syncthreads();
#pragma unroll
        for (int kc = 0; kc < 16; ++kc) {
            float wv[4], xv[4];
#pragma unroll
            for (int i = 0; i < 4; ++i) wv[i] = sW[kc][ty + i * 16];
#pragma unroll
            for (int i = 0; i < 4; ++i) xv[i] = sX[kc][tx + i * 16];
#pragma unroll
            for (int oy = 0; oy < 4; ++oy)
#pragma unroll
                for (int nx = 0; nx < 4; ++nx)
                    acc[oy][nx] += wv[oy] * xv[nx];
        }
        __syncthreads();
    }

#pragma unroll
    for (int oy = 0; oy < 4; ++oy) {
        int o = o0 + ty + oy * 16;
        float bv = bias[o];
#pragma unroll
        for (int nx = 0; nx < 4; ++nx) {
            Y[((size_t)b * M + o) * NPIX + n0 + tx + nx * 16] = acc[oy][nx] + bv;
        }
    }
}

// ---------------------------------------------------------------------------
// Depthwise 3x3, SAME padding. One block per (b,c) plane.
// ---------------------------------------------------------------------------
__global__ __launch_bounds__(256) void dwconv3x3_kernel(
    const float* __restrict__ X,   // [B][C][48][48]
    const float* __restrict__ Wp,  // [C][1][3][3]
    const float* __restrict__ bp,  // [C]
    float* __restrict__ Y)
{
    const int bc = blockIdx.x;       // b*256 + c
    const int c = bc & 255;
    const float* xp = X + (size_t)bc * NPIX;
    float w[9];
#pragma unroll
    for (int i = 0; i < 9; ++i) w[i] = Wp[c * 9 + i];
    const float bb = bp[c];

    for (int p = threadIdx.x; p < NPIX; p += 256) {
        int i = p / HW, j = p % HW;
        float acc = bb;
#pragma unroll
        for (int di = -1; di <= 1; ++di) {
            int ii = i + di;
            if (ii < 0 || ii >= HW) continue;
#pragma unroll
            for (int dj = -1; dj <= 1; ++dj) {
                int jj = j + dj;
                if (jj < 0 || jj >= HW) continue;
                acc += xp[ii * HW + jj] * w[(di + 1) * 3 + (dj + 1)];
            }
        }
        Y[(size_t)bc * NPIX + p] = acc;
    }
}

// ---------------------------------------------------------------------------
// Flash attention, fp32. One block = one 64-query tile of one (b,h).
// Q/K come from the qk buffer ([B][512][N], head h: rows h*64..h*64+31 = Q,
// +32.. = K), V from v4 ([B][256][N], head h: rows h*32..h*32+31).
// Online softmax over 36 j-tiles of 64.
// ---------------------------------------------------------------------------
__global__ __launch_bounds__(256) void flash_attn_kernel(
    const float* __restrict__ QK,   // [B][512][NPIX]
    const float* __restrict__ V4,   // [B][256][NPIX]
    float* __restrict__ O)          // [B][256][NPIX]
{
    const int i0 = blockIdx.x * 64;
    const int bh = blockIdx.y;
    const int b  = bh >> 3, hh = bh & 7;
    const float* Qp = QK + ((size_t)b * 512 + hh * 64) * NPIX;
    const float* Kp = Qp + (size_t)HD * NPIX;
    const float* Vp = V4 + ((size_t)b * 256 + hh * HD) * NPIX;
    float*       Op = O  + ((size_t)b * 256 + hh * HD) * NPIX;

    __shared__ float sQ[HD][65];
    __shared__ float sK[HD][65];
    __shared__ float sV[HD][65];
    __shared__ float sS[64][65];
    __shared__ float sm[64], sl[64], salpha[64];
    __shared__ float sred[64][4];

    const int t  = threadIdx.x;
    const int tx = t & 15;
    const int ty = t >> 4;

    // load Q tile (pre-scaled)
    for (int idx = t; idx < HD * 64; idx += 256) {
        int d = idx >> 6, i = idx & 63;
        sQ[d][i] = Qp[(size_t)d * NPIX + i0 + i] * SCALE_CONST;
    }
    if (t < 64) { sm[t] = -1e30f; sl[t] = 0.f; }

    float oacc[2][4] = {};   // [dd][ii]: d = ty*2+dd, i = tx + ii*16

    for (int j0 = 0; j0 < NPIX; j0 += 64) {
        // load K,V tiles
        for (int idx = t; idx < HD * 64; idx += 256) {
            int d = idx >> 6, j = idx & 63;
            sK[d][j] = Kp[(size_t)d * NPIX + j0 + j];
            sV[d][j] = Vp[(size_t)d * NPIX + j0 + j];
        }
        __syncthreads();

        // ---- Phase A: S = Q^T K (64x64), 4x4 per thread ----
        float sa[4][4] = {};
#pragma unroll 8
        for (int d = 0; d < HD; ++d) {
            float qv[4], kv[4];
#pragma unroll
            for (int i = 0; i < 4; ++i) qv[i] = sQ[d][ty + i * 16];
#pragma unroll
            for (int i = 0; i < 4; ++i) kv[i] = sK[d][tx + i * 16];
#pragma unroll
            for (int iy = 0; iy < 4; ++iy)
#pragma unroll
                for (int jx = 0; jx < 4; ++jx)
                    sa[iy][jx] += qv[iy] * kv[jx];
        }
#pragma unroll
        for (int iy = 0; iy < 4; ++iy)
#pragma unroll
            for (int jx = 0; jx < 4; ++jx)
                sS[ty + iy * 16][tx + jx * 16] = sa[iy][jx];
        __syncthreads();

        // ---- Phase B: online softmax (4 threads per row) ----
        {
            const int r = t >> 2;
            const int p = t & 3;
            float mx = -1e30f;
            for (int j = p * 16; j < p * 16 + 16; ++j) mx = fmaxf(mx, sS[r][j]);
            sred[r][p] = mx;
            __syncthreads();
            if (p == 0) {
                float tm = fmaxf(fmaxf(sred[r][0], sred[r][1]), fmaxf(sred[r][2], sred[r][3]));
                float mo = sm[r];
                float mn = fmaxf(mo, tm);
                salpha[r] = __expf(mo - mn);
                sm[r] = mn;
            }
            __syncthreads();
            float mn = sm[r];
            float s = 0.f;
            for (int j = p * 16; j < p * 16 + 16; ++j) {
                float e = __expf(sS[r][j] - mn);
                sS[r][j] = e;
                s += e;
            }
            sred[r][p] = s;
            __syncthreads();
            if (p == 0) {
                sl[r] = salpha[r] * sl[r] + sred[r][0] + sred[r][1] + sred[r][2] + sred[r][3];
            }
            __syncthreads();
        }

        // ---- Phase C: O = alpha*O + P V^T ----
        float al[4];
#pragma unroll
        for (int ii = 0; ii < 4; ++ii) al[ii] = salpha[tx + ii * 16];
#pragma unroll
        for (int dd = 0; dd < 2; ++dd)
#pragma unroll
            for (int ii = 0; ii < 4; ++ii) oacc[dd][ii] *= al[ii];

#pragma unroll 4
        for (int j = 0; j < 64; ++j) {
            float pv[4], vv[2];
#pragma unroll
            for (int ii = 0; ii < 4; ++ii) pv[ii] = sS[tx + ii * 16][j];
#pragma unroll
            for (int dd = 0; dd < 2; ++dd) vv[dd] = sV[ty * 2 + dd][j];
#pragma unroll
            for (int dd = 0; dd < 2; ++dd)
#pragma unroll
                for (int ii = 0; ii < 4; ++ii)
                    oacc[dd][ii] += vv[dd] * pv[ii];
        }
        __syncthreads();   // protect sK/sV/sS before next tile load
    }

    // final: divide by l, store
    float invl[4];
#pragma unroll
    for (int ii = 0; ii < 4; ++ii) invl[ii] = 1.f / sl[tx + ii * 16];
#pragma unroll
    for (int dd = 0; dd < 2; ++dd) {
        int d = ty * 2 + dd;
#pragma unroll
        for (int ii = 0; ii < 4; ++ii) {
            Op[(size_t)d * NPIX + i0 + tx + ii * 16] = oacc[dd][ii] * invl[ii];
        }
    }
}

// ---------------------------------------------------------------------------
extern "C" void kernel_launch(void* const* d_in, const int* in_sizes, int n_in,
                              void* d_out, int out_size, void* d_ws, size_t ws_size,
                              hipStream_t stream) {
    const float* x      = (const float*)d_in[0];
    const float* w_qk   = (const float*)d_in[1];
    const float* b_qk   = (const float*)d_in[2];
    const float* w_v    = (const float*)d_in[3];
    const float* b_v    = (const float*)d_in[4];
    const float* w_pe   = (const float*)d_in[5];
    const float* b_pe   = (const float*)d_in[6];
    const float* w_proj = (const float*)d_in[7];
    const float* b_proj = (const float*)d_in[8];
    float* out = (float*)d_out;

    float* ws    = (float*)d_ws;
    float* ws_qk = ws;                          // 4*512*2304 = 4,718,592 floats
    float* ws_v4 = ws_qk + (size_t)4 * 512 * NPIX;   // 2,359,296 floats
    float* ws_pe = ws_v4 + (size_t)4 * 256 * NPIX;
    float* ws_ao = ws_pe + (size_t)4 * 256 * NPIX;   // total ~47.2 MB

    // qk = conv1x1(x, w_qk) : M=512
    conv1x1_kernel<<<dim3(36, 8, 4), 256, 0, stream>>>(w_qk, b_qk, x, nullptr, ws_qk, 512);
    // v4 = conv1x1(x, w_v) : M=256
    conv1x1_kernel<<<dim3(36, 4, 4), 256, 0, stream>>>(w_v, b_v, x, nullptr, ws_v4, 256);
    // pe = dwconv3x3(v4)
    dwconv3x3_kernel<<<dim3(4 * 256), 256, 0, stream>>>(ws_v4, w_pe, b_pe, ws_pe);
    // attention
    flash_attn_kernel<<<dim3(36, 32), 256, 0, stream>>>(ws_qk, ws_v4, ws_ao);
    // out = conv1x1(attn_out + pe, w_proj)
    conv1x1_kernel<<<dim3(36, 4, 4), 256, 0, stream>>>(w_proj, b_proj, ws_ao, ws_pe, out, 256);
}

// Round 2
// 349.791 us; speedup vs baseline: 2.4286x; 2.4286x over previous
//
#include <hip/hip_runtime.h>
#include <hip/hip_bf16.h>
#include <math.h>

#define NPIX 2304      // 48*48
#define HW 48
#define CDIM 256
#define NHEADS 8
#define HD 32
#define SCALE_CONST 0.17677669529663687f   // 32^-0.5

typedef __attribute__((ext_vector_type(8))) short  short8v;
typedef __attribute__((ext_vector_type(4))) short  short4v;
typedef __attribute__((ext_vector_type(4))) float  floatx4;

__device__ inline short f2bf(float f) {
    unsigned u = __builtin_bit_cast(unsigned, f);
    u += 0x7FFFu + ((u >> 16) & 1u);       // round-to-nearest-even
    return (short)(u >> 16);
}

// ---------------------------------------------------------------------------
// QK 1x1-conv: GEMM then write bf16 transposed Q^T [bh][i][d] (pre-scaled) and
// K^T [bh][j][d].  M=512 fixed.
// ---------------------------------------------------------------------------
__global__ __launch_bounds__(256) void conv_qk_kernel(
    const float* __restrict__ W,     // [512][256]
    const float* __restrict__ bias,  // [512]
    const float* __restrict__ X,     // [B][256][NPIX]
    short* __restrict__ QT,          // [B*8][NPIX][32] bf16
    short* __restrict__ KT)          // [B*8][NPIX][32] bf16
{
    __shared__ float sW[16][65];
    __shared__ float sX[16][65];
    const int b  = blockIdx.z;
    const int o0 = blockIdx.y * 64;
    const int n0 = blockIdx.x * 64;
    const int t  = threadIdx.x;
    const int tx = t & 15;
    const int ty = t >> 4;

    const float* Xb = X + (size_t)b * CDIM * NPIX;
    float acc[4][4] = {};

    for (int k0 = 0; k0 < CDIM; k0 += 16) {
#pragma unroll
        for (int i = 0; i < 4; ++i) {
            int idx = t + i * 256;
            int o = idx >> 4, kc = idx & 15;
            sW[kc][o] = W[(size_t)(o0 + o) * CDIM + k0 + kc];
        }
#pragma unroll
        for (int i = 0; i < 4; ++i) {
            int idx = t + i * 256;
            int kc = idx >> 6, n = idx & 63;
            sX[kc][n] = Xb[(size_t)(k0 + kc) * NPIX + n0 + n];
        }
        __syncthreads();
#pragma unroll
        for (int kc = 0; kc < 16; ++kc) {
            float wv[4], xv[4];
#pragma unroll
            for (int i = 0; i < 4; ++i) wv[i] = sW[kc][ty + i * 16];
#pragma unroll
            for (int i = 0; i < 4; ++i) xv[i] = sX[kc][tx + i * 16];
#pragma unroll
            for (int oy = 0; oy < 4; ++oy)
#pragma unroll
                for (int nx = 0; nx < 4; ++nx)
                    acc[oy][nx] += wv[oy] * xv[nx];
        }
        __syncthreads();
    }

    const int h = o0 >> 6;            // head (o0 is 64-aligned)
#pragma unroll
    for (int oy = 0; oy < 4; ++oy) {
        int r = ty + oy * 16;         // 0..63 within head
        int o = o0 + r;
        float bv = bias[o];
        bool isQ = (r < 32);
        int d = isQ ? r : r - 32;
        short* dst = isQ ? QT : KT;
        float scl = isQ ? SCALE_CONST : 1.0f;
#pragma unroll
        for (int nx = 0; nx < 4; ++nx) {
            int n = n0 + tx + nx * 16;
            dst[((size_t)(b * 8 + h) * NPIX + n) * HD + d] = f2bf((acc[oy][nx] + bv) * scl);
        }
    }
}

// ---------------------------------------------------------------------------
// V 1x1-conv: writes fp32 v4 (for dwconv/pe) AND bf16 natural-layout copy.
// ---------------------------------------------------------------------------
__global__ __launch_bounds__(256) void conv_v_kernel(
    const float* __restrict__ W,     // [256][256]
    const float* __restrict__ bias,
    const float* __restrict__ X,
    float* __restrict__ Y,           // [B][256][NPIX] fp32
    short* __restrict__ Yb)          // [B][256][NPIX] bf16
{
    __shared__ float sW[16][65];
    __shared__ float sX[16][65];
    const int b  = blockIdx.z;
    const int o0 = blockIdx.y * 64;
    const int n0 = blockIdx.x * 64;
    const int t  = threadIdx.x;
    const int tx = t & 15;
    const int ty = t >> 4;

    const float* Xb = X + (size_t)b * CDIM * NPIX;
    float acc[4][4] = {};

    for (int k0 = 0; k0 < CDIM; k0 += 16) {
#pragma unroll
        for (int i = 0; i < 4; ++i) {
            int idx = t + i * 256;
            int o = idx >> 4, kc = idx & 15;
            sW[kc][o] = W[(size_t)(o0 + o) * CDIM + k0 + kc];
        }
#pragma unroll
        for (int i = 0; i < 4; ++i) {
            int idx = t + i * 256;
            int kc = idx >> 6, n = idx & 63;
            sX[kc][n] = Xb[(size_t)(k0 + kc) * NPIX + n0 + n];
        }
        __syncthreads();
#pragma unroll
        for (int kc = 0; kc < 16; ++kc) {
            float wv[4], xv[4];
#pragma unroll
            for (int i = 0; i < 4; ++i) wv[i] = sW[kc][ty + i * 16];
#pragma unroll
            for (int i = 0; i < 4; ++i) xv[i] = sX[kc][tx + i * 16];
#pragma unroll
            for (int oy = 0; oy < 4; ++oy)
#pragma unroll
                for (int nx = 0; nx < 4; ++nx)
                    acc[oy][nx] += wv[oy] * xv[nx];
        }
        __syncthreads();
    }

#pragma unroll
    for (int oy = 0; oy < 4; ++oy) {
        int o = o0 + ty + oy * 16;
        float bv = bias[o];
#pragma unroll
        for (int nx = 0; nx < 4; ++nx) {
            int n = n0 + tx + nx * 16;
            float v = acc[oy][nx] + bv;
            Y [((size_t)b * 256 + o) * NPIX + n] = v;
            Yb[((size_t)b * 256 + o) * NPIX + n] = f2bf(v);
        }
    }
}

// ---------------------------------------------------------------------------
// Generic 1x1-conv (fp32), used for the projection: Y = W*(X+Xadd)+b
// ---------------------------------------------------------------------------
__global__ __launch_bounds__(256) void conv1x1_kernel(
    const float* __restrict__ W,
    const float* __restrict__ bias,
    const float* __restrict__ X,
    const float* __restrict__ Xadd,
    float* __restrict__ Y,
    int M)
{
    __shared__ float sW[16][65];
    __shared__ float sX[16][65];
    const int b  = blockIdx.z;
    const int o0 = blockIdx.y * 64;
    const int n0 = blockIdx.x * 64;
    const int t  = threadIdx.x;
    const int tx = t & 15;
    const int ty = t >> 4;

    const float* Xb  = X + (size_t)b * CDIM * NPIX;
    const float* Xab = Xadd ? Xadd + (size_t)b * CDIM * NPIX : nullptr;
    float acc[4][4] = {};

    for (int k0 = 0; k0 < CDIM; k0 += 16) {
#pragma unroll
        for (int i = 0; i < 4; ++i) {
            int idx = t + i * 256;
            int o = idx >> 4, kc = idx & 15;
            sW[kc][o] = W[(size_t)(o0 + o) * CDIM + k0 + kc];
        }
#pragma unroll
        for (int i = 0; i < 4; ++i) {
            int idx = t + i * 256;
            int kc = idx >> 6, n = idx & 63;
            float v = Xb[(size_t)(k0 + kc) * NPIX + n0 + n];
            if (Xab) v += Xab[(size_t)(k0 + kc) * NPIX + n0 + n];
            sX[kc][n] = v;
        }
        __syncthreads();
#pragma unroll
        for (int kc = 0; kc < 16; ++kc) {
            float wv[4], xv[4];
#pragma unroll
            for (int i = 0; i < 4; ++i) wv[i] = sW[kc][ty + i * 16];
#pragma unroll
            for (int i = 0; i < 4; ++i) xv[i] = sX[kc][tx + i * 16];
#pragma unroll
            for (int oy = 0; oy < 4; ++oy)
#pragma unroll
                for (int nx = 0; nx < 4; ++nx)
                    acc[oy][nx] += wv[oy] * xv[nx];
        }
        __syncthreads();
    }

#pragma unroll
    for (int oy = 0; oy < 4; ++oy) {
        int o = o0 + ty + oy * 16;
        float bv = bias[o];
#pragma unroll
        for (int nx = 0; nx < 4; ++nx)
            Y[((size_t)b * M + o) * NPIX + n0 + tx + nx * 16] = acc[oy][nx] + bv;
    }
}

// ---------------------------------------------------------------------------
// Depthwise 3x3 (unchanged)
// ---------------------------------------------------------------------------
__global__ __launch_bounds__(256) void dwconv3x3_kernel(
    const float* __restrict__ X,
    const float* __restrict__ Wp,
    const float* __restrict__ bp,
    float* __restrict__ Y)
{
    const int bc = blockIdx.x;
    const int c = bc & 255;
    const float* xp = X + (size_t)bc * NPIX;
    float w[9];
#pragma unroll
    for (int i = 0; i < 9; ++i) w[i] = Wp[c * 9 + i];
    const float bb = bp[c];

    for (int p = threadIdx.x; p < NPIX; p += 256) {
        int i = p / HW, j = p % HW;
        float acc = bb;
#pragma unroll
        for (int di = -1; di <= 1; ++di) {
            int ii = i + di;
            if (ii < 0 || ii >= HW) continue;
#pragma unroll
            for (int dj = -1; dj <= 1; ++dj) {
                int jj = j + dj;
                if (jj < 0 || jj >= HW) continue;
                acc += xp[ii * HW + jj] * w[(di + 1) * 3 + (dj + 1)];
            }
        }
        Y[(size_t)bc * NPIX + p] = acc;
    }
}

// ---------------------------------------------------------------------------
// MFMA flash attention. Block = 64 queries of one (b,h); 4 waves.
// S'[j][i] = K^T Q via mfma_f32_16x16x32_bf16; online softmax fp32;
// O[d][i] += V P via MFMA with P round-tripped through LDS as bf16 [i][j].
// ---------------------------------------------------------------------------
// LDS layout (bytes): strides chosen 16B-aligned, <=2-way bank aliasing
#define SQT_OFF   0           // 64 rows x 80 B (40 bf16, 32 used)
#define SKT_OFF   5120        // 64 rows x 80 B
#define SV_OFF    10240       // 32 rows x 144 B (72 bf16, 64 used)
#define SP_OFF    14848       // 64 rows x 144 B
#define SREDM_OFF 24064       // 4 x 64 fp32
#define SREDS_OFF 25088       // 4 x 64 fp32
#define SM_OFF    26112       // 64 fp32
#define SL_OFF    26368       // 64 fp32
#define SMEM_BYTES 26624

__global__ __launch_bounds__(256) void flash_attn_mfma(
    const short* __restrict__ QT,   // [bh][i][32] bf16 (scaled)
    const short* __restrict__ KT,   // [bh][j][32] bf16
    const short* __restrict__ VB,   // [b][256][NPIX] bf16
    float* __restrict__ AO)         // [b][256][NPIX] fp32
{
    __shared__ __align__(16) char smem[SMEM_BYTES];

    const int i0 = blockIdx.x * 64;
    const int bh = blockIdx.y;
    const int b  = bh >> 3, hh = bh & 7;

    const short* QTp = QT + (size_t)bh * NPIX * HD;
    const short* KTp = KT + (size_t)bh * NPIX * HD;
    const short* Vp  = VB + (size_t)(b * 256 + hh * HD) * NPIX;
    float*       Op  = AO + (size_t)(b * 256 + hh * HD) * NPIX;

    const int t    = threadIdx.x;
    const int lane = t & 63;
    const int w    = t >> 6;
    const int l15  = lane & 15;
    const int quad = lane >> 4;

    float* sM = (float*)(smem + SM_OFF);
    float* sL = (float*)(smem + SL_OFF);
    float (*sRedM)[64] = (float (*)[64])(smem + SREDM_OFF);
    float (*sRedS)[64] = (float (*)[64])(smem + SREDS_OFF);

    // ---- stage Q tile: [64 i][32 d] -> sQt rows of 80B ----
    {
        int4 qst = ((const int4*)(QTp + (size_t)i0 * HD))[t];
        *(int4*)(smem + SQT_OFF + (t >> 2) * 80 + (t & 3) * 16) = qst;
    }
    if (t < 64) { sM[t] = -1e30f; sL[t] = 0.f; }

    const int ib0  = w >> 1;     // this wave's PV i-blocks: ib0, ib0+2
    const int dblk = w & 1;      // this wave's PV d-block

    floatx4 oacc[2];
    oacc[0] = (floatx4){0.f, 0.f, 0.f, 0.f};
    oacc[1] = (floatx4){0.f, 0.f, 0.f, 0.f};

    // prefetch tile 0
    int4 kst = ((const int4*)(KTp))[t];
    int4 vst = *(const int4*)(Vp + (size_t)(t >> 3) * NPIX + (t & 7) * 8);

    for (int it = 0; it < 36; ++it) {
        const int j0n = (it + 1) * 64;
        __syncthreads();   // prev PV done: sKt/sV/sP free
        *(int4*)(smem + SKT_OFF + (t >> 2) * 80 + (t & 3) * 16) = kst;
        *(int4*)(smem + SV_OFF + (t >> 3) * 144 + (t & 7) * 16) = vst;
        if (it + 1 < 36) {
            kst = ((const int4*)(KTp + (size_t)j0n * HD))[t];
            vst = *(const int4*)(Vp + (size_t)(t >> 3) * NPIX + j0n + (t & 7) * 8);
        }
        __syncthreads();   // tiles ready

        // ---- S' = K^T Q : wave w covers j-strip w (16 j) x 64 i ----
        short8v afrag = *(const short8v*)(smem + SKT_OFF + (w * 16 + l15) * 80 + quad * 16);
        floatx4 sacc[4];
#pragma unroll
        for (int ib = 0; ib < 4; ++ib) {
            short8v bfrag = *(const short8v*)(smem + SQT_OFF + (ib * 16 + l15) * 80 + quad * 16);
            sacc[ib] = __builtin_amdgcn_mfma_f32_16x16x32_bf16(
                afrag, bfrag, (floatx4){0.f, 0.f, 0.f, 0.f}, 0, 0, 0);
        }

        // ---- strip max per column i ----
#pragma unroll
        for (int ib = 0; ib < 4; ++ib) {
            float mp = fmaxf(fmaxf(sacc[ib][0], sacc[ib][1]), fmaxf(sacc[ib][2], sacc[ib][3]));
            mp = fmaxf(mp, __shfl_xor(mp, 16));
            mp = fmaxf(mp, __shfl_xor(mp, 32));
            if (quad == 0) sRedM[w][ib * 16 + l15] = mp;
        }
        __syncthreads();   // (A) strip maxes visible

        float mnew[4], alpha[4];
#pragma unroll
        for (int ib = 0; ib < 4; ++ib) {
            int ii = ib * 16 + l15;
            float tm = fmaxf(fmaxf(sRedM[0][ii], sRedM[1][ii]),
                             fmaxf(sRedM[2][ii], sRedM[3][ii]));
            float mo = sM[ii];
            float mn = fmaxf(mo, tm);
            mnew[ib]  = mn;
            alpha[ib] = __expf(mo - mn);
        }

        // ---- exp, write P (bf16) to sP[i][j], partial sums ----
#pragma unroll
        for (int ib = 0; ib < 4; ++ib) {
            int ii = ib * 16 + l15;
            float s = 0.f;
            short4v pb;
#pragma unroll
            for (int r = 0; r < 4; ++r) {
                float e = __expf(sacc[ib][r] - mnew[ib]);
                s += e;
                pb[r] = f2bf(e);
            }
            *(short4v*)(smem + SP_OFF + ii * 144 + (w * 16 + quad * 4) * 2) = pb;
            s += __shfl_xor(s, 16);
            s += __shfl_xor(s, 32);
            if (quad == 0) sRedS[w][ii] = s;
        }

        // rescale O accumulators by alpha of their columns
#pragma unroll
        for (int r = 0; r < 4; ++r) {
            oacc[0][r] *= alpha[ib0];
            oacc[1][r] *= alpha[ib0 + 2];
        }
        __syncthreads();   // (B) sP + partial sums visible

        // state update (wave 0)
        if (t < 64) {
            float tm = fmaxf(fmaxf(sRedM[0][t], sRedM[1][t]),
                             fmaxf(sRedM[2][t], sRedM[3][t]));
            float mo = sM[t];
            float mn = fmaxf(mo, tm);
            float al = __expf(mo - mn);
            sL[t] = al * sL[t] + sRedS[0][t] + sRedS[1][t] + sRedS[2][t] + sRedS[3][t];
            sM[t] = mn;
        }

        // ---- PV: O[d][i] += V * P ----
        short8v va0 = *(const short8v*)(smem + SV_OFF + (dblk * 16 + l15) * 144 + quad * 16);
        short8v va1 = *(const short8v*)(smem + SV_OFF + (dblk * 16 + l15) * 144 + 64 + quad * 16);
#pragma unroll
        for (int tt = 0; tt < 2; ++tt) {
            int ib = ib0 + tt * 2;
            short8v pf0 = *(const short8v*)(smem + SP_OFF + (ib * 16 + l15) * 144 + quad * 16);
            short8v pf1 = *(const short8v*)(smem + SP_OFF + (ib * 16 + l15) * 144 + 64 + quad * 16);
            oacc[tt] = __builtin_amdgcn_mfma_f32_16x16x32_bf16(va0, pf0, oacc[tt], 0, 0, 0);
            oacc[tt] = __builtin_amdgcn_mfma_f32_16x16x32_bf16(va1, pf1, oacc[tt], 0, 0, 0);
        }
    }

    __syncthreads();   // final sL visible
#pragma unroll
    for (int tt = 0; tt < 2; ++tt) {
        int ib = ib0 + tt * 2;
        float invl = 1.0f / sL[ib * 16 + l15];
#pragma unroll
        for (int r = 0; r < 4; ++r) {
            int d = dblk * 16 + quad * 4 + r;
            Op[(size_t)d * NPIX + i0 + ib * 16 + l15] = oacc[tt][r] * invl;
        }
    }
}

// ---------------------------------------------------------------------------
extern "C" void kernel_launch(void* const* d_in, const int* in_sizes, int n_in,
                              void* d_out, int out_size, void* d_ws, size_t ws_size,
                              hipStream_t stream) {
    const float* x      = (const float*)d_in[0];
    const float* w_qk   = (const float*)d_in[1];
    const float* b_qk   = (const float*)d_in[2];
    const float* w_v    = (const float*)d_in[3];
    const float* b_v    = (const float*)d_in[4];
    const float* w_pe   = (const float*)d_in[5];
    const float* b_pe   = (const float*)d_in[6];
    const float* w_proj = (const float*)d_in[7];
    const float* b_proj = (const float*)d_in[8];
    float* out = (float*)d_out;

    char* wsb = (char*)d_ws;
    float* ws_v4 = (float*)wsb;                 wsb += (size_t)4 * 256 * NPIX * 4;
    float* ws_pe = (float*)wsb;                 wsb += (size_t)4 * 256 * NPIX * 4;
    float* ws_ao = (float*)wsb;                 wsb += (size_t)4 * 256 * NPIX * 4;
    short* ws_qt = (short*)wsb;                 wsb += (size_t)32 * NPIX * HD * 2;
    short* ws_kt = (short*)wsb;                 wsb += (size_t)32 * NPIX * HD * 2;
    short* ws_vb = (short*)wsb;                 wsb += (size_t)4 * 256 * NPIX * 2;

    conv_qk_kernel<<<dim3(36, 8, 4), 256, 0, stream>>>(w_qk, b_qk, x, ws_qt, ws_kt);
    conv_v_kernel <<<dim3(36, 4, 4), 256, 0, stream>>>(w_v, b_v, x, ws_v4, ws_vb);
    dwconv3x3_kernel<<<dim3(1024), 256, 0, stream>>>(ws_v4, w_pe, b_pe, ws_pe);
    flash_attn_mfma<<<dim3(36, 32), 256, 0, stream>>>(ws_qt, ws_kt, ws_vb, ws_ao);
    conv1x1_kernel<<<dim3(36, 4, 4), 256, 0, stream>>>(w_proj, b_proj, ws_ao, ws_pe, out, 256);
}

// Round 3
// 282.868 us; speedup vs baseline: 3.0032x; 1.2366x over previous
//
#include <hip/hip_runtime.h>
#include <hip/hip_bf16.h>
#include <math.h>

#define NPIX 2304      // 48*48
#define HW 48
#define CDIM 256
#define NHEADS 8
#define HD 32
#define SCALE_CONST 0.17677669529663687f   // 32^-0.5

typedef __attribute__((ext_vector_type(8))) short  short8v;
typedef __attribute__((ext_vector_type(4))) short  short4v;
typedef __attribute__((ext_vector_type(4))) float  floatx4;

__device__ inline short f2bf(float f) {
    unsigned u = __builtin_bit_cast(unsigned, f);
    u += 0x7FFFu + ((u >> 16) & 1u);       // round-to-nearest-even
    return (short)(u >> 16);
}
__device__ inline float bf2f(unsigned short us) {
    return __builtin_bit_cast(float, (unsigned)us << 16);
}

// ---------------------------------------------------------------------------
// Weight fp32 -> bf16 conversion (w_qk 512x256, w_v 256x256, w_proj 256x256)
// ---------------------------------------------------------------------------
__global__ __launch_bounds__(256) void convert_w_kernel(
    const float* __restrict__ wqk, const float* __restrict__ wv,
    const float* __restrict__ wp,
    short* __restrict__ wqkb, short* __restrict__ wvb, short* __restrict__ wpb)
{
    int base = blockIdx.x * 256 + threadIdx.x;
#pragma unroll
    for (int i = 0; i < 4; ++i) {
        int idx = base + i * 65536;
        if (idx < 131072) {
            wqkb[idx] = f2bf(wqk[idx]);
        } else if (idx < 196608) {
            wvb[idx - 131072] = f2bf(wv[idx - 131072]);
        } else {
            wpb[idx - 196608] = f2bf(wp[idx - 196608]);
        }
    }
}

// ---------------------------------------------------------------------------
// Transpose+cast: dst[b][n][c] = bf16(src[b][c][n] (+ add[b][c][n]))
// 64c x 64n tiles via fp32 LDS (65-pad, conflict-free both phases).
// ---------------------------------------------------------------------------
__global__ __launch_bounds__(256) void transpose_cast_kernel(
    const float* __restrict__ src,   // [B][256][NPIX]
    const float* __restrict__ add,   // nullable
    short* __restrict__ dst)         // [B][NPIX][256]
{
    __shared__ float sT[64][65];
    const int b = blockIdx.z, c0 = blockIdx.y * 64, n0 = blockIdx.x * 64;
    const int t = threadIdx.x;
    const float* sp = src + ((size_t)b * 256 + c0) * NPIX + n0;
    const float* ap = add ? add + ((size_t)b * 256 + c0) * NPIX + n0 : nullptr;
    const int cl = t >> 6, n = t & 63;
#pragma unroll
    for (int it = 0; it < 16; ++it) {
        int c = it * 4 + cl;
        float v = sp[(size_t)c * NPIX + n];
        if (ap) v += ap[(size_t)c * NPIX + n];
        sT[n][c] = v;
    }
    __syncthreads();
    const int nr = t >> 2, q = t & 3;
    short out[16];
#pragma unroll
    for (int j = 0; j < 16; ++j) out[j] = f2bf(sT[nr][q * 16 + j]);
    short* dp = dst + ((size_t)b * NPIX + n0 + nr) * 256 + c0 + q * 16;
    *(int4*)dp = *(int4*)out;
    *(int4*)(dp + 8) = *(int4*)(out + 8);
}

// ---------------------------------------------------------------------------
// MFMA GEMM core: one wave computes a 16(o) x 64(n) strip, K=256.
// A row m=l15 (k-contig from W bf16 [M][256]); B row n=l15 (k-contig from
// T[b][n][256]).  acc[ib] covers n-tile ib; C/D: col(l15)=n, row(quad*4+r)=o.
// ---------------------------------------------------------------------------
__device__ inline void conv_gemm_wave(const short* __restrict__ Arow,
                                      const short* __restrict__ Brow,
                                      floatx4 acc[4])
{
#pragma unroll
    for (int s = 0; s < 8; ++s) {
        short8v af = *(const short8v*)(Arow + s * 32);
#pragma unroll
        for (int ib = 0; ib < 4; ++ib) {
            short8v bf = *(const short8v*)(Brow + (size_t)ib * 16 * CDIM + s * 32);
            acc[ib] = __builtin_amdgcn_mfma_f32_16x16x32_bf16(af, bf, acc[ib], 0, 0, 0);
        }
    }
}

// ---------------------------------------------------------------------------
// QK conv: W[512][256]b x XT -> QT/KT [bh][n][32] bf16 (Q pre-scaled).
// Output tile transposed through LDS for coalesced 16B stores.
// ---------------------------------------------------------------------------
__global__ __launch_bounds__(256) void conv_qk_mfma(
    const short* __restrict__ Wb,    // [512][256] bf16
    const float* __restrict__ bias,  // [512]
    const short* __restrict__ XT,    // [B][NPIX][256] bf16
    short* __restrict__ QT,          // [B*8][NPIX][32]
    short* __restrict__ KT)
{
    __shared__ short sT[64][72];     // [n][oh], rows 144B (16B aligned)
    const int n0 = blockIdx.x * 64;
    const int h  = blockIdx.y;
    const int b  = blockIdx.z;
    const int t = threadIdx.x, lane = t & 63, w = t >> 6;
    const int l15 = lane & 15, quad = lane >> 4;

    const short* Arow = Wb + (size_t)(h * 64 + w * 16 + l15) * CDIM + quad * 8;
    const short* Brow = XT + ((size_t)b * NPIX + n0 + l15) * CDIM + quad * 8;

    floatx4 acc[4];
#pragma unroll
    for (int ib = 0; ib < 4; ++ib) acc[ib] = (floatx4){0.f, 0.f, 0.f, 0.f};
    conv_gemm_wave(Arow, Brow, acc);

    float bv[4];
#pragma unroll
    for (int r = 0; r < 4; ++r) bv[r] = bias[h * 64 + w * 16 + quad * 4 + r];
    const bool isQ = (w < 2);
    const float scl = isQ ? SCALE_CONST : 1.0f;

#pragma unroll
    for (int ib = 0; ib < 4; ++ib) {
        short4v pb;
#pragma unroll
        for (int r = 0; r < 4; ++r) pb[r] = f2bf((acc[ib][r] + bv[r]) * scl);
        *(short4v*)&sT[ib * 16 + l15][w * 16 + quad * 4] = pb;
    }
    __syncthreads();

    const int nr = t >> 2, q = t & 3;
    const int bh = b * 8 + h;
#pragma unroll
    for (int cc = 0; cc < 2; ++cc) {
        int chunk = q * 2 + cc;        // 0..7
        int o8 = chunk * 8;
        int4 val = *(int4*)&sT[nr][o8];
        short* dst = (o8 < 32)
            ? QT + ((size_t)bh * NPIX + n0 + nr) * HD + o8
            : KT + ((size_t)bh * NPIX + n0 + nr) * HD + (o8 - 32);
        *(int4*)dst = val;
    }
}

// ---------------------------------------------------------------------------
// V conv: W[256][256]b x XT -> VB [b][256][NPIX] bf16 (natural layout).
// ---------------------------------------------------------------------------
__global__ __launch_bounds__(256) void conv_v_mfma(
    const short* __restrict__ Wb,
    const float* __restrict__ bias,
    const short* __restrict__ XT,
    short* __restrict__ VB)
{
    const int n0 = blockIdx.x * 64;
    const int og = blockIdx.y;
    const int b  = blockIdx.z;
    const int t = threadIdx.x, lane = t & 63, w = t >> 6;
    const int l15 = lane & 15, quad = lane >> 4;

    const short* Arow = Wb + (size_t)(og * 64 + w * 16 + l15) * CDIM + quad * 8;
    const short* Brow = XT + ((size_t)b * NPIX + n0 + l15) * CDIM + quad * 8;

    floatx4 acc[4];
#pragma unroll
    for (int ib = 0; ib < 4; ++ib) acc[ib] = (floatx4){0.f, 0.f, 0.f, 0.f};
    conv_gemm_wave(Arow, Brow, acc);

#pragma unroll
    for (int r = 0; r < 4; ++r) {
        int o = og * 64 + w * 16 + quad * 4 + r;
        float bb = bias[o];
#pragma unroll
        for (int ib = 0; ib < 4; ++ib) {
            VB[((size_t)b * 256 + o) * NPIX + n0 + ib * 16 + l15] = f2bf(acc[ib][r] + bb);
        }
    }
}

// ---------------------------------------------------------------------------
// Proj conv: W[256][256]b x ST -> out fp32 [b][256][NPIX].
// ---------------------------------------------------------------------------
__global__ __launch_bounds__(256) void conv_proj_mfma(
    const short* __restrict__ Wb,
    const float* __restrict__ bias,
    const short* __restrict__ ST,    // [B][NPIX][256] bf16 (= ao + pe, transposed)
    float* __restrict__ out)
{
    const int n0 = blockIdx.x * 64;
    const int og = blockIdx.y;
    const int b  = blockIdx.z;
    const int t = threadIdx.x, lane = t & 63, w = t >> 6;
    const int l15 = lane & 15, quad = lane >> 4;

    const short* Arow = Wb + (size_t)(og * 64 + w * 16 + l15) * CDIM + quad * 8;
    const short* Brow = ST + ((size_t)b * NPIX + n0 + l15) * CDIM + quad * 8;

    floatx4 acc[4];
#pragma unroll
    for (int ib = 0; ib < 4; ++ib) acc[ib] = (floatx4){0.f, 0.f, 0.f, 0.f};
    conv_gemm_wave(Arow, Brow, acc);

#pragma unroll
    for (int r = 0; r < 4; ++r) {
        int o = og * 64 + w * 16 + quad * 4 + r;
        float bb = bias[o];
#pragma unroll
        for (int ib = 0; ib < 4; ++ib) {
            out[((size_t)b * 256 + o) * NPIX + n0 + ib * 16 + l15] = acc[ib][r] + bb;
        }
    }
}

// ---------------------------------------------------------------------------
// Depthwise 3x3 on bf16 input -> fp32 PE
// ---------------------------------------------------------------------------
__global__ __launch_bounds__(256) void dwconv3x3_kernel(
    const short* __restrict__ X,     // [B][256][NPIX] bf16
    const float* __restrict__ Wp,
    const float* __restrict__ bp,
    float* __restrict__ Y)           // fp32
{
    const int bc = blockIdx.x;
    const int c = bc & 255;
    const unsigned short* xp = (const unsigned short*)X + (size_t)bc * NPIX;
    float w[9];
#pragma unroll
    for (int i = 0; i < 9; ++i) w[i] = Wp[c * 9 + i];
    const float bb = bp[c];

    for (int p = threadIdx.x; p < NPIX; p += 256) {
        int i = p / HW, j = p % HW;
        float acc = bb;
#pragma unroll
        for (int di = -1; di <= 1; ++di) {
            int ii = i + di;
            if (ii < 0 || ii >= HW) continue;
#pragma unroll
            for (int dj = -1; dj <= 1; ++dj) {
                int jj = j + dj;
                if (jj < 0 || jj >= HW) continue;
                acc += bf2f(xp[ii * HW + jj]) * w[(di + 1) * 3 + (dj + 1)];
            }
        }
        Y[(size_t)bc * NPIX + p] = acc;
    }
}

// ---------------------------------------------------------------------------
// MFMA flash attention (unchanged from round 2).
// ---------------------------------------------------------------------------
#define SQT_OFF   0
#define SKT_OFF   5120
#define SV_OFF    10240
#define SP_OFF    14848
#define SREDM_OFF 24064
#define SREDS_OFF 25088
#define SM_OFF    26112
#define SL_OFF    26368
#define SMEM_BYTES 26624

__global__ __launch_bounds__(256) void flash_attn_mfma(
    const short* __restrict__ QT,
    const short* __restrict__ KT,
    const short* __restrict__ VB,
    float* __restrict__ AO)
{
    __shared__ __align__(16) char smem[SMEM_BYTES];

    const int i0 = blockIdx.x * 64;
    const int bh = blockIdx.y;
    const int b  = bh >> 3, hh = bh & 7;

    const short* QTp = QT + (size_t)bh * NPIX * HD;
    const short* KTp = KT + (size_t)bh * NPIX * HD;
    const short* Vp  = VB + (size_t)(b * 256 + hh * HD) * NPIX;
    float*       Op  = AO + (size_t)(b * 256 + hh * HD) * NPIX;

    const int t    = threadIdx.x;
    const int lane = t & 63;
    const int w    = t >> 6;
    const int l15  = lane & 15;
    const int quad = lane >> 4;

    float* sM = (float*)(smem + SM_OFF);
    float* sL = (float*)(smem + SL_OFF);
    float (*sRedM)[64] = (float (*)[64])(smem + SREDM_OFF);
    float (*sRedS)[64] = (float (*)[64])(smem + SREDS_OFF);

    {
        int4 qst = ((const int4*)(QTp + (size_t)i0 * HD))[t];
        *(int4*)(smem + SQT_OFF + (t >> 2) * 80 + (t & 3) * 16) = qst;
    }
    if (t < 64) { sM[t] = -1e30f; sL[t] = 0.f; }

    const int ib0  = w >> 1;
    const int dblk = w & 1;

    floatx4 oacc[2];
    oacc[0] = (floatx4){0.f, 0.f, 0.f, 0.f};
    oacc[1] = (floatx4){0.f, 0.f, 0.f, 0.f};

    int4 kst = ((const int4*)(KTp))[t];
    int4 vst = *(const int4*)(Vp + (size_t)(t >> 3) * NPIX + (t & 7) * 8);

    for (int it = 0; it < 36; ++it) {
        const int j0n = (it + 1) * 64;
        __syncthreads();
        *(int4*)(smem + SKT_OFF + (t >> 2) * 80 + (t & 3) * 16) = kst;
        *(int4*)(smem + SV_OFF + (t >> 3) * 144 + (t & 7) * 16) = vst;
        if (it + 1 < 36) {
            kst = ((const int4*)(KTp + (size_t)j0n * HD))[t];
            vst = *(const int4*)(Vp + (size_t)(t >> 3) * NPIX + j0n + (t & 7) * 8);
        }
        __syncthreads();

        short8v afrag = *(const short8v*)(smem + SKT_OFF + (w * 16 + l15) * 80 + quad * 16);
        floatx4 sacc[4];
#pragma unroll
        for (int ib = 0; ib < 4; ++ib) {
            short8v bfrag = *(const short8v*)(smem + SQT_OFF + (ib * 16 + l15) * 80 + quad * 16);
            sacc[ib] = __builtin_amdgcn_mfma_f32_16x16x32_bf16(
                afrag, bfrag, (floatx4){0.f, 0.f, 0.f, 0.f}, 0, 0, 0);
        }

#pragma unroll
        for (int ib = 0; ib < 4; ++ib) {
            float mp = fmaxf(fmaxf(sacc[ib][0], sacc[ib][1]), fmaxf(sacc[ib][2], sacc[ib][3]));
            mp = fmaxf(mp, __shfl_xor(mp, 16));
            mp = fmaxf(mp, __shfl_xor(mp, 32));
            if (quad == 0) sRedM[w][ib * 16 + l15] = mp;
        }
        __syncthreads();

        float mnew[4], alpha[4];
#pragma unroll
        for (int ib = 0; ib < 4; ++ib) {
            int ii = ib * 16 + l15;
            float tm = fmaxf(fmaxf(sRedM[0][ii], sRedM[1][ii]),
                             fmaxf(sRedM[2][ii], sRedM[3][ii]));
            float mo = sM[ii];
            float mn = fmaxf(mo, tm);
            mnew[ib]  = mn;
            alpha[ib] = __expf(mo - mn);
        }

#pragma unroll
        for (int ib = 0; ib < 4; ++ib) {
            int ii = ib * 16 + l15;
            float s = 0.f;
            short4v pb;
#pragma unroll
            for (int r = 0; r < 4; ++r) {
                float e = __expf(sacc[ib][r] - mnew[ib]);
                s += e;
                pb[r] = f2bf(e);
            }
            *(short4v*)(smem + SP_OFF + ii * 144 + (w * 16 + quad * 4) * 2) = pb;
            s += __shfl_xor(s, 16);
            s += __shfl_xor(s, 32);
            if (quad == 0) sRedS[w][ii] = s;
        }

#pragma unroll
        for (int r = 0; r < 4; ++r) {
            oacc[0][r] *= alpha[ib0];
            oacc[1][r] *= alpha[ib0 + 2];
        }
        __syncthreads();

        if (t < 64) {
            float tm = fmaxf(fmaxf(sRedM[0][t], sRedM[1][t]),
                             fmaxf(sRedM[2][t], sRedM[3][t]));
            float mo = sM[t];
            float mn = fmaxf(mo, tm);
            float al = __expf(mo - mn);
            sL[t] = al * sL[t] + sRedS[0][t] + sRedS[1][t] + sRedS[2][t] + sRedS[3][t];
            sM[t] = mn;
        }

        short8v va0 = *(const short8v*)(smem + SV_OFF + (dblk * 16 + l15) * 144 + quad * 16);
        short8v va1 = *(const short8v*)(smem + SV_OFF + (dblk * 16 + l15) * 144 + 64 + quad * 16);
#pragma unroll
        for (int tt = 0; tt < 2; ++tt) {
            int ib = ib0 + tt * 2;
            short8v pf0 = *(const short8v*)(smem + SP_OFF + (ib * 16 + l15) * 144 + quad * 16);
            short8v pf1 = *(const short8v*)(smem + SP_OFF + (ib * 16 + l15) * 144 + 64 + quad * 16);
            oacc[tt] = __builtin_amdgcn_mfma_f32_16x16x32_bf16(va0, pf0, oacc[tt], 0, 0, 0);
            oacc[tt] = __builtin_amdgcn_mfma_f32_16x16x32_bf16(va1, pf1, oacc[tt], 0, 0, 0);
        }
    }

    __syncthreads();
#pragma unroll
    for (int tt = 0; tt < 2; ++tt) {
        int ib = ib0 + tt * 2;
        float invl = 1.0f / sL[ib * 16 + l15];
#pragma unroll
        for (int r = 0; r < 4; ++r) {
            int d = dblk * 16 + quad * 4 + r;
            Op[(size_t)d * NPIX + i0 + ib * 16 + l15] = oacc[tt][r] * invl;
        }
    }
}

// ---------------------------------------------------------------------------
extern "C" void kernel_launch(void* const* d_in, const int* in_sizes, int n_in,
                              void* d_out, int out_size, void* d_ws, size_t ws_size,
                              hipStream_t stream) {
    const float* x      = (const float*)d_in[0];
    const float* w_qk   = (const float*)d_in[1];
    const float* b_qk   = (const float*)d_in[2];
    const float* w_v    = (const float*)d_in[3];
    const float* b_v    = (const float*)d_in[4];
    const float* w_pe   = (const float*)d_in[5];
    const float* b_pe   = (const float*)d_in[6];
    const float* w_proj = (const float*)d_in[7];
    const float* b_proj = (const float*)d_in[8];
    float* out = (float*)d_out;

    char* wsb = (char*)d_ws;
    short* ws_xt  = (short*)wsb;  wsb += (size_t)4 * NPIX * 256 * 2;   // XT bf16
    short* ws_qt  = (short*)wsb;  wsb += (size_t)32 * NPIX * HD * 2;   // QT bf16
    short* ws_kt  = (short*)wsb;  wsb += (size_t)32 * NPIX * HD * 2;   // KT bf16
    short* ws_vb  = (short*)wsb;  wsb += (size_t)4 * 256 * NPIX * 2;   // VB bf16
    float* ws_ao  = (float*)wsb;  wsb += (size_t)4 * 256 * NPIX * 4;   // AO fp32
    float* ws_pe  = (float*)wsb;  wsb += (size_t)4 * 256 * NPIX * 4;   // PE fp32
    short* ws_st  = (short*)wsb;  wsb += (size_t)4 * NPIX * 256 * 2;   // ST bf16
    short* ws_wqk = (short*)wsb;  wsb += (size_t)512 * 256 * 2;
    short* ws_wv  = (short*)wsb;  wsb += (size_t)256 * 256 * 2;
    short* ws_wp  = (short*)wsb;  wsb += (size_t)256 * 256 * 2;

    convert_w_kernel<<<dim3(256), 256, 0, stream>>>(w_qk, w_v, w_proj, ws_wqk, ws_wv, ws_wp);
    transpose_cast_kernel<<<dim3(36, 4, 4), 256, 0, stream>>>(x, nullptr, ws_xt);
    conv_qk_mfma<<<dim3(36, 8, 4), 256, 0, stream>>>(ws_wqk, b_qk, ws_xt, ws_qt, ws_kt);
    conv_v_mfma<<<dim3(36, 4, 4), 256, 0, stream>>>(ws_wv, b_v, ws_xt, ws_vb);
    flash_attn_mfma<<<dim3(36, 32), 256, 0, stream>>>(ws_qt, ws_kt, ws_vb, ws_ao);
    dwconv3x3_kernel<<<dim3(1024), 256, 0, stream>>>(ws_vb, w_pe, b_pe, ws_pe);
    transpose_cast_kernel<<<dim3(36, 4, 4), 256, 0, stream>>>(ws_ao, ws_pe, ws_st);
    conv_proj_mfma<<<dim3(36, 4, 4), 256, 0, stream>>>(ws_wp, b_proj, ws_st, out);
}

// Round 6
// 182.684 us; speedup vs baseline: 4.6501x; 1.5484x over previous
//
#include <hip/hip_runtime.h>
#include <hip/hip_bf16.h>

#define NPIX 2304      // 48*48
#define HW 48
#define CDIM 256
#define NHEADS 8
#define HD 32
#define SCALE_CONST 0.17677669529663687f   // 32^-0.5
#define LOG2E 1.4426950408889634f

typedef __attribute__((ext_vector_type(8))) short  short8v;
typedef __attribute__((ext_vector_type(4))) short  short4v;
typedef __attribute__((ext_vector_type(4))) float  floatx4;

__device__ inline short f2bf(float f) {
    unsigned u = __builtin_bit_cast(unsigned, f);
    u += 0x7FFFu + ((u >> 16) & 1u);       // round-to-nearest-even
    return (short)(u >> 16);
}
__device__ inline float bf2f(unsigned short us) {
    return __builtin_bit_cast(float, (unsigned)us << 16);
}
__device__ inline float fexp2(float x) {
    return __builtin_amdgcn_exp2f(x);      // v_exp_f32 (base-2 native)
}

// ---------------------------------------------------------------------------
// Prep: blocks 0..575 transpose+cast x -> XT[b][n][256] bf16;
//       blocks 576..639 convert weights fp32->bf16.
// ---------------------------------------------------------------------------
__global__ __launch_bounds__(256) void prep_kernel(
    const float* __restrict__ x,     // [B][256][NPIX]
    short* __restrict__ XT,          // [B][NPIX][256]
    const float* __restrict__ wqk, const float* __restrict__ wv,
    const float* __restrict__ wp,
    short* __restrict__ wqkb, short* __restrict__ wvb, short* __restrict__ wpb)
{
    const int bx = blockIdx.x;
    const int t = threadIdx.x;
    if (bx >= 576) {
        int tid = (bx - 576) * 256 + t;
        for (int idx = tid; idx < 262144; idx += 16384) {
            if (idx < 131072)       wqkb[idx] = f2bf(wqk[idx]);
            else if (idx < 196608)  wvb[idx - 131072] = f2bf(wv[idx - 131072]);
            else                    wpb[idx - 196608] = f2bf(wp[idx - 196608]);
        }
        return;
    }
    __shared__ float sT[64][65];
    const int nt = bx % 36, ct = (bx / 36) & 3, b = bx / 144;
    const int c0 = ct * 64, n0 = nt * 64;
    const float* sp = x + ((size_t)b * 256 + c0) * NPIX + n0;
    const int cl = t >> 6, n = t & 63;
#pragma unroll
    for (int it = 0; it < 16; ++it) {
        int c = it * 4 + cl;
        sT[n][c] = sp[(size_t)c * NPIX + n];
    }
    __syncthreads();
    const int nr = t >> 2, q = t & 3;
    short out[16];
#pragma unroll
    for (int j = 0; j < 16; ++j) out[j] = f2bf(sT[nr][q * 16 + j]);
    short* dp = XT + ((size_t)b * NPIX + n0 + nr) * 256 + c0 + q * 16;
    *(int4*)dp = *(int4*)out;
    *(int4*)(dp + 8) = *(int4*)(out + 8);
}

// ---------------------------------------------------------------------------
// Fused QK+V conv (MFMA). Grid y: 0..7 = QK head h (64 rows: 32 Q + 32 K),
// 8..11 = V row-group. B-operand (XT tile, 64n x 256c) staged in LDS.
// Q rows scaled by SCALE*LOG2E (flash uses exp2).
// ---------------------------------------------------------------------------
#define XROW 528   // bytes per LDS row (512 + 16 pad)

__device__ inline void stage_xt_tile(const short* __restrict__ src_base,
                                     char* __restrict__ sX, int t)
{
    // 64 rows x 512B = 32KB; thread t covers row (t>>3) and (t>>3)+32,
    // 64B (32 shorts) each at column (t&7)*32.
    const short* src = src_base + (size_t)(t >> 3) * 256 + (t & 7) * 32;
    char* dst = sX + (t >> 3) * XROW + (t & 7) * 64;
#pragma unroll
    for (int rr = 0; rr < 2; ++rr) {
        const short* s = src + rr * 32 * 256;
        char* d = dst + rr * 32 * XROW;
        *(int4*)d        = *(const int4*)s;
        *(int4*)(d + 16) = *(const int4*)(s + 8);
        *(int4*)(d + 32) = *(const int4*)(s + 16);
        *(int4*)(d + 48) = *(const int4*)(s + 24);
    }
}

__global__ __launch_bounds__(256) void conv_qkv_mfma(
    const short* __restrict__ Wqk,   // [512][256] bf16
    const short* __restrict__ Wv,    // [256][256] bf16
    const float* __restrict__ bqk,   // [512]
    const float* __restrict__ bv,    // [256]
    const short* __restrict__ XT,    // [B][NPIX][256] bf16
    short* __restrict__ QT,          // [B*8][NPIX][32]
    short* __restrict__ KT,          // [B*8][NPIX][32]
    short* __restrict__ VB)          // [B][256][NPIX]
{
    __shared__ __align__(16) char sX[64 * XROW];
    const int n0 = blockIdx.x * 64;
    const int og = blockIdx.y;
    const int b  = blockIdx.z;
    const int t = threadIdx.x, lane = t & 63, w = t >> 6;
    const int l15 = lane & 15, quad = lane >> 4;

    stage_xt_tile(XT + ((size_t)b * NPIX + n0) * 256, sX, t);
    __syncthreads();

    const bool isV = (og >= 8);
    const short* Wb = isV ? Wv + (size_t)((og - 8) * 64 + w * 16 + l15) * CDIM
                          : Wqk + (size_t)(og * 64 + w * 16 + l15) * CDIM;

    floatx4 acc[4];
#pragma unroll
    for (int ib = 0; ib < 4; ++ib) acc[ib] = (floatx4){0.f, 0.f, 0.f, 0.f};

#pragma unroll
    for (int s = 0; s < 8; ++s) {
        short8v af = *(const short8v*)(Wb + s * 32 + quad * 8);
#pragma unroll
        for (int ib = 0; ib < 4; ++ib) {
            short8v bf = *(const short8v*)(sX + (ib * 16 + l15) * XROW + s * 64 + quad * 16);
            acc[ib] = __builtin_amdgcn_mfma_f32_16x16x32_bf16(af, bf, acc[ib], 0, 0, 0);
        }
    }

    if (!isV) {
        // rows r64 = w*16 + quad*4 + r within head; Q if w<2
        const bool isQ = (w < 2);
        const int d0 = (w & 1) * 16 + quad * 4;
        const float scl = isQ ? SCALE_CONST * LOG2E : 1.0f;
        float bvv[4];
#pragma unroll
        for (int r = 0; r < 4; ++r) bvv[r] = bqk[og * 64 + w * 16 + quad * 4 + r];
        short* base = (isQ ? QT : KT) + (size_t)(b * 8 + og) * NPIX * HD;
#pragma unroll
        for (int ib = 0; ib < 4; ++ib) {
            short pb[4];
#pragma unroll
            for (int r = 0; r < 4; ++r) pb[r] = f2bf((acc[ib][r] + bvv[r]) * scl);
            *(short4v*)(base + (size_t)(n0 + ib * 16 + l15) * HD + d0) = *(short4v*)pb;
        }
    } else {
        const int o0 = (og - 8) * 64 + w * 16 + quad * 4;
#pragma unroll
        for (int r = 0; r < 4; ++r) {
            int o = o0 + r;
            float bb = bv[o];
#pragma unroll
            for (int ib = 0; ib < 4; ++ib) {
                VB[((size_t)b * 256 + o) * NPIX + n0 + ib * 16 + l15] = f2bf(acc[ib][r] + bb);
            }
        }
    }
}

// ---------------------------------------------------------------------------
// Depthwise 3x3 on bf16 input, plane staged in LDS -> fp32 PE
// ---------------------------------------------------------------------------
__global__ __launch_bounds__(256) void dwconv3x3_kernel(
    const short* __restrict__ X,     // [B][256][NPIX] bf16
    const float* __restrict__ Wp,
    const float* __restrict__ bp,
    float* __restrict__ Y)           // fp32
{
    __shared__ short spl[NPIX];
    const int bc = blockIdx.x;
    const int c = bc & 255;
    const short* xp = X + (size_t)bc * NPIX;
    const int t = threadIdx.x;
    for (int idx = t; idx < NPIX / 8; idx += 256)
        *(int4*)&spl[idx * 8] = *(const int4*)(xp + idx * 8);
    float w[9];
#pragma unroll
    for (int i = 0; i < 9; ++i) w[i] = Wp[c * 9 + i];
    const float bb = bp[c];
    __syncthreads();

    for (int p = t; p < NPIX; p += 256) {
        int i = p / HW, j = p % HW;
        float acc = bb;
#pragma unroll
        for (int di = -1; di <= 1; ++di) {
            int ii = i + di;
            if (ii < 0 || ii >= HW) continue;
#pragma unroll
            for (int dj = -1; dj <= 1; ++dj) {
                int jj = j + dj;
                if (jj < 0 || jj >= HW) continue;
                acc += bf2f((unsigned short)spl[ii * HW + jj]) * w[(di + 1) * 3 + (dj + 1)];
            }
        }
        Y[(size_t)bc * NPIX + p] = acc;
    }
}

// ---------------------------------------------------------------------------
// Flash attention, wave-private softmax. Block = 64 queries of one (b,h),
// 4 waves; wave w owns i-block w (16 queries). 1 barrier/iter (K/V dbuf).
// Epilogue fuses +PE, bf16 cast, transposed store to ST[b][n][256].
// ---------------------------------------------------------------------------
#define SK0 0            // 64 x 80B
#define SK1 5120
#define SV0 10240        // 32 x 144B
#define SV1 14848
#define SP0 19456        // 4 waves x 16 x 144B
#define FL_SMEM 28672

__global__ __launch_bounds__(256) void flash_attn_mfma(
    const short* __restrict__ QT,   // [bh][i][32] bf16, scaled by SCALE*LOG2E
    const short* __restrict__ KT,   // [bh][j][32] bf16
    const short* __restrict__ VB,   // [b][256][NPIX] bf16
    const float* __restrict__ PE,   // [b][256][NPIX] fp32
    short* __restrict__ ST)         // [b][NPIX][256] bf16  (= attn_out + pe)^T
{
    __shared__ __align__(16) char smem[FL_SMEM];

    const int i0 = blockIdx.x * 64;
    const int bh = blockIdx.y;
    const int b  = bh >> 3, hh = bh & 7;

    const short* KTp = KT + (size_t)bh * NPIX * HD;
    const short* Vp  = VB + (size_t)(b * 256 + hh * HD) * NPIX;

    const int t    = threadIdx.x;
    const int lane = t & 63;
    const int w    = t >> 6;
    const int l15  = lane & 15;
    const int quad = lane >> 4;

    // Q fragment for this wave: B-operand, row i = i0 + w*16 + l15, k=quad*8..
    const short8v qfrag = *(const short8v*)(
        QT + ((size_t)bh * NPIX + i0 + w * 16 + l15) * HD + quad * 8);

    char* const sPw = smem + SP0 + w * (16 * 144);

    float m_i = -1e30f, l_i = 0.f;
    floatx4 oacc[2];
    oacc[0] = (floatx4){0.f, 0.f, 0.f, 0.f};
    oacc[1] = (floatx4){0.f, 0.f, 0.f, 0.f};

    // staging slices for this thread
    const short* ksrc = KTp + (size_t)(t >> 2) * HD + (t & 3) * 8;
    const short* vsrc = Vp + (size_t)(t >> 3) * NPIX + (t & 7) * 8;
    const int koff = (t >> 2) * 80 + (t & 3) * 16;
    const int voff = (t >> 3) * 144 + (t & 7) * 16;

    int4 kst = *(const int4*)ksrc;
    int4 vst = *(const int4*)vsrc;

    for (int it = 0; it < 36; ++it) {
        char* bufK = smem + ((it & 1) ? SK1 : SK0);
        char* bufV = smem + ((it & 1) ? SV1 : SV0);
        *(int4*)(bufK + koff) = kst;
        *(int4*)(bufV + voff) = vst;
        if (it + 1 < 36) {
            kst = *(const int4*)(ksrc + (size_t)(it + 1) * 64 * HD);
            vst = *(const int4*)(vsrc + (it + 1) * 64);
        }
        __syncthreads();

        // ---- S' = K Q^T : acc[jb] covers j-block jb x own 16 i ----
        floatx4 sacc[4];
#pragma unroll
        for (int jb = 0; jb < 4; ++jb) {
            short8v af = *(const short8v*)(bufK + (jb * 16 + l15) * 80 + quad * 16);
            sacc[jb] = __builtin_amdgcn_mfma_f32_16x16x32_bf16(
                af, qfrag, (floatx4){0.f, 0.f, 0.f, 0.f}, 0, 0, 0);
        }

        // ---- in-lane + quad max over the 16 j values (one i per lane) ----
        float mx = sacc[0][0];
#pragma unroll
        for (int jb = 0; jb < 4; ++jb)
#pragma unroll
            for (int r = 0; r < 4; ++r) mx = fmaxf(mx, sacc[jb][r]);
        mx = fmaxf(mx, __shfl_xor(mx, 16));
        mx = fmaxf(mx, __shfl_xor(mx, 32));

        float mn = fmaxf(m_i, mx);
        float alpha = fexp2(m_i - mn);
        m_i = mn;

        // ---- exp2, P -> LDS (wave-private), partial sum ----
        float s = 0.f;
#pragma unroll
        for (int jb = 0; jb < 4; ++jb) {
            short pb[4];
#pragma unroll
            for (int r = 0; r < 4; ++r) {
                float e = fexp2(sacc[jb][r] - mn);
                s += e;
                pb[r] = f2bf(e);
            }
            *(short4v*)(sPw + l15 * 144 + (jb * 16 + quad * 4) * 2) = *(short4v*)pb;
        }
        s += __shfl_xor(s, 16);
        s += __shfl_xor(s, 32);
        l_i = alpha * l_i + s;

#pragma unroll
        for (int r = 0; r < 4; ++r) { oacc[0][r] *= alpha; oacc[1][r] *= alpha; }

        // ---- PV: O[32 d][own 16 i] += V P  (P same-wave, no barrier) ----
#pragma unroll
        for (int ks = 0; ks < 2; ++ks) {
            short8v pf = *(const short8v*)(sPw + l15 * 144 + ks * 64 + quad * 16);
#pragma unroll
            for (int db = 0; db < 2; ++db) {
                short8v vf = *(const short8v*)(bufV + (db * 16 + l15) * 144 + ks * 64 + quad * 16);
                oacc[db] = __builtin_amdgcn_mfma_f32_16x16x32_bf16(vf, pf, oacc[db], 0, 0, 0);
            }
        }
    }

    // ---- epilogue: /l, +PE, bf16, transposed store ----
    const float invl = 1.0f / l_i;
    const int i = i0 + w * 16 + l15;
    const float* PEp = PE + ((size_t)b * 256 + hh * HD) * NPIX + i;
    short* stp = ST + ((size_t)b * NPIX + i) * 256 + hh * HD;
#pragma unroll
    for (int db = 0; db < 2; ++db) {
        short pb[4];
#pragma unroll
        for (int r = 0; r < 4; ++r) {
            int d = db * 16 + quad * 4 + r;
            float v = oacc[db][r] * invl + PEp[(size_t)d * NPIX];
            pb[r] = f2bf(v);
        }
        *(short4v*)(stp + db * 16 + quad * 4) = *(short4v*)pb;
    }
}

// ---------------------------------------------------------------------------
// Proj conv (MFMA), B-operand (ST tile) staged in LDS. Output fp32 natural.
// ---------------------------------------------------------------------------
__global__ __launch_bounds__(256) void conv_proj_mfma(
    const short* __restrict__ Wb,    // [256][256] bf16
    const float* __restrict__ bias,
    const short* __restrict__ ST,    // [B][NPIX][256] bf16
    float* __restrict__ out)
{
    __shared__ __align__(16) char sX[64 * XROW];
    const int n0 = blockIdx.x * 64;
    const int og = blockIdx.y;
    const int b  = blockIdx.z;
    const int t = threadIdx.x, lane = t & 63, w = t >> 6;
    const int l15 = lane & 15, quad = lane >> 4;

    stage_xt_tile(ST + ((size_t)b * NPIX + n0) * 256, sX, t);
    __syncthreads();

    const short* Arow = Wb + (size_t)(og * 64 + w * 16 + l15) * CDIM;
    floatx4 acc[4];
#pragma unroll
    for (int ib = 0; ib < 4; ++ib) acc[ib] = (floatx4){0.f, 0.f, 0.f, 0.f};
#pragma unroll
    for (int s = 0; s < 8; ++s) {
        short8v af = *(const short8v*)(Arow + s * 32 + quad * 8);
#pragma unroll
        for (int ib = 0; ib < 4; ++ib) {
            short8v bf = *(const short8v*)(sX + (ib * 16 + l15) * XROW + s * 64 + quad * 16);
            acc[ib] = __builtin_amdgcn_mfma_f32_16x16x32_bf16(af, bf, acc[ib], 0, 0, 0);
        }
    }

#pragma unroll
    for (int r = 0; r < 4; ++r) {
        int o = og * 64 + w * 16 + quad * 4 + r;
        float bb = bias[o];
#pragma unroll
        for (int ib = 0; ib < 4; ++ib)
            out[((size_t)b * 256 + o) * NPIX + n0 + ib * 16 + l15] = acc[ib][r] + bb;
    }
}

// ---------------------------------------------------------------------------
extern "C" void kernel_launch(void* const* d_in, const int* in_sizes, int n_in,
                              void* d_out, int out_size, void* d_ws, size_t ws_size,
                              hipStream_t stream) {
    const float* x      = (const float*)d_in[0];
    const float* w_qk   = (const float*)d_in[1];
    const float* b_qk   = (const float*)d_in[2];
    const float* w_v    = (const float*)d_in[3];
    const float* b_v    = (const float*)d_in[4];
    const float* w_pe   = (const float*)d_in[5];
    const float* b_pe   = (const float*)d_in[6];
    const float* w_proj = (const float*)d_in[7];
    const float* b_proj = (const float*)d_in[8];
    float* out = (float*)d_out;

    char* wsb = (char*)d_ws;
    short* ws_xt  = (short*)wsb;  wsb += (size_t)4 * NPIX * 256 * 2;   // XT bf16
    short* ws_qt  = (short*)wsb;  wsb += (size_t)32 * NPIX * HD * 2;   // QT bf16
    short* ws_kt  = (short*)wsb;  wsb += (size_t)32 * NPIX * HD * 2;   // KT bf16
    short* ws_vb  = (short*)wsb;  wsb += (size_t)4 * 256 * NPIX * 2;   // VB bf16
    float* ws_pe  = (float*)wsb;  wsb += (size_t)4 * 256 * NPIX * 4;   // PE fp32
    short* ws_st  = (short*)wsb;  wsb += (size_t)4 * NPIX * 256 * 2;   // ST bf16
    short* ws_wqk = (short*)wsb;  wsb += (size_t)512 * 256 * 2;
    short* ws_wv  = (short*)wsb;  wsb += (size_t)256 * 256 * 2;
    short* ws_wp  = (short*)wsb;  wsb += (size_t)256 * 256 * 2;

    prep_kernel<<<dim3(640), 256, 0, stream>>>(x, ws_xt, w_qk, w_v, w_proj,
                                               ws_wqk, ws_wv, ws_wp);
    conv_qkv_mfma<<<dim3(36, 12, 4), 256, 0, stream>>>(ws_wqk, ws_wv, b_qk, b_v,
                                                       ws_xt, ws_qt, ws_kt, ws_vb);
    dwconv3x3_kernel<<<dim3(1024), 256, 0, stream>>>(ws_vb, w_pe, b_pe, ws_pe);
    flash_attn_mfma<<<dim3(36, 32), 256, 0, stream>>>(ws_qt, ws_kt, ws_vb, ws_pe, ws_st);
    conv_proj_mfma<<<dim3(36, 4, 4), 256, 0, stream>>>(ws_wp, b_proj, ws_st, out);
}